// Round 1
// baseline (495.253 us; speedup 1.0000x reference)
//
#include <hip/hip_runtime.h>
#include <hip/hip_bf16.h>

// Problem constants
// B=64, C=16, F=2048, J=25 ; EMBED=64, CLASSES=5, NJ=12
// stats used: s2=max, s3=q25, s4=xs[1023], s5=q75, s6=mean, s7=std(ddof=1),
//             s8=max-min, s9=kurtosis(mean(z^4)-3)
// stat1/W1/b1 path is dead code in the reference. features[...,24] unused.

#define F_LEN 2048
#define JTOT 25
#define BC 1024          // B*C
#define STATS_PER_BC 192 // 16 s * 12 j

// ---------------------------------------------------------------------------
// Per-array processing: moments + in-register wave bitonic sort + store stats
// x: 32 elements per lane, blocked layout: lane l holds ranks [32l, 32l+32)
// after the ascending sort.
// ---------------------------------------------------------------------------
__device__ __forceinline__ void process_array(float (&x)[32], int lane,
                                              float* __restrict__ stat2,
                                              int bc, int j) {
  // ---- moments (two-pass central) ----
  float sum = 0.f;
#pragma unroll
  for (int e = 0; e < 32; ++e) sum += x[e];
#pragma unroll
  for (int off = 32; off; off >>= 1) sum += __shfl_xor(sum, off, 64);
  const float m = sum * (1.0f / 2048.0f);

  float c2 = 0.f, c4 = 0.f;
#pragma unroll
  for (int e = 0; e < 32; ++e) {
    float d = x[e] - m;
    float dd = d * d;
    c2 += dd;
    c4 += dd * dd;
  }
#pragma unroll
  for (int off = 32; off; off >>= 1) {
    c2 += __shfl_xor(c2, off, 64);
    c4 += __shfl_xor(c4, off, 64);
  }
  const float var = c2 * (1.0f / 2047.0f);   // ddof=1
  const float sd = sqrtf(var);
  const float kurt = (c4 * (1.0f / 2048.0f)) / (var * var) - 3.0f;

  // ---- bitonic sort over 2048 = 64 lanes x 32 regs (blocked layout) ----
#pragma unroll
  for (int kp = 1; kp <= 11; ++kp) {
    const int k = 1 << kp;
#pragma unroll
    for (int jp = kp - 1; jp >= 0; --jp) {
      const int st = 1 << jp;
      if (st >= 32) {
        const int mask = st >> 5;
        const bool keepmin =
            (((lane & mask) == 0) == (((lane << 5) & k) == 0));
#pragma unroll
        for (int e = 0; e < 32; ++e) {
          float o = __shfl_xor(x[e], mask, 64);
          x[e] = keepmin ? fminf(x[e], o) : fmaxf(x[e], o);
        }
      } else {
#pragma unroll
        for (int e = 0; e < 32; ++e) {
          if ((e & st) == 0) {
            const bool up = ((((lane << 5) | e) & k) == 0);
            float a = x[e], b = x[e + st];
            float lo = fminf(a, b), hi = fmaxf(a, b);
            x[e] = up ? lo : hi;
            x[e + st] = up ? hi : lo;
          }
        }
      }
    }
  }

  // ---- extract order statistics (rank r -> lane r>>5, reg r&31) ----
  const float mn   = __shfl(x[0], 0, 64);
  const float a511 = __shfl(x[31], 15, 64);
  const float a512 = __shfl(x[0], 16, 64);
  const float amed = __shfl(x[31], 31, 64);
  const float a1535 = __shfl(x[31], 47, 64);
  const float a1536 = __shfl(x[0], 48, 64);
  const float mx   = __shfl(x[31], 63, 64);

  if (lane == 0) {
    const float q25 = 0.25f * a511 + 0.75f * a512;   // pos=511.75
    const float q75 = 0.75f * a1535 + 0.25f * a1536; // pos=1535.25
    const int jj = (j < 12) ? j : j - 12;
    const int sb = (j < 12) ? 0 : 8;
    float st[8] = {mx, q25, amed, q75, m, sd, mx - mn, kurt};
    float* o = stat2 + (bc * 16 + sb) * 12 + jj;
#pragma unroll
    for (int s = 0; s < 8; ++s) o[s * 12] = st[s];
  }
}

// ---------------------------------------------------------------------------
// Kernel A: one wave per pair of j-channels of one (b,c) slab.
// 1024 bc * 12 pairs = 12288 waves = 3072 blocks of 256 threads.
// XCD swizzle: blockIdx&7 picks a bc partition so same-slab waves share an L2.
// ---------------------------------------------------------------------------
__global__ __launch_bounds__(256) void stat_kernel(
    const float* __restrict__ Fp, float* __restrict__ stat2) {
  const int g = blockIdx.x;
  const int xcd = g & 7;
  const int mm = g >> 3;            // 0..383
  const int bc = xcd * 128 + mm / 3;
  const int grp = mm % 3;
  const int w = threadIdx.x >> 6;
  const int lane = threadIdx.x & 63;
  const int pair = grp * 4 + w;     // 0..11
  const int j0 = pair * 2;

  const float* base =
      Fp + ((size_t)bc * F_LEN + (size_t)lane * 32) * JTOT + j0;

  float x[32], y[32];
#pragma unroll
  for (int e = 0; e < 32; ++e) {
    x[e] = base[e * JTOT];
    y[e] = base[e * JTOT + 1];
  }

  process_array(x, lane, stat2, bc, j0);
  process_array(y, lane, stat2, bc, j0 + 1);
}

// ---------------------------------------------------------------------------
// Kernel B: fuse (einsum over c,j with W2 + b2) then logits (@ Wl.T + bl).
// One block per batch element b. flat2[b, e*16+s] ; logits[b,k].
// ---------------------------------------------------------------------------
__global__ __launch_bounds__(256) void fuse_kernel(
    const float* __restrict__ stat2, const float* __restrict__ W2,
    const float* __restrict__ b2, const float* __restrict__ Wl,
    const float* __restrict__ bl, float* __restrict__ out) {
  __shared__ float s_stat[16 * STATS_PER_BC]; // 3072 floats: [c][s][j]
  __shared__ float s_flat[1024];
  __shared__ float s_red[4];

  const int b = blockIdx.x;
  const int t = threadIdx.x;

  for (int idx = t; idx < 16 * STATS_PER_BC; idx += 256)
    s_stat[idx] = stat2[b * (16 * STATS_PER_BC) + idx];
  __syncthreads();

  const int e = t & 63;
  const int q = t >> 6; // s-quarter: s in {4q..4q+3}
  float acc[4] = {0.f, 0.f, 0.f, 0.f};
  for (int c = 0; c < 16; ++c) {
    const float* wrow = W2 + (e * 16 + c) * 12;
    const float* srow = s_stat + c * STATS_PER_BC;
#pragma unroll
    for (int j = 0; j < 12; ++j) {
      const float wv = wrow[j];
#pragma unroll
      for (int ss = 0; ss < 4; ++ss)
        acc[ss] += srow[(q * 4 + ss) * 12 + j] * wv;
    }
  }
  const float bb = b2[e];
#pragma unroll
  for (int ss = 0; ss < 4; ++ss)
    s_flat[e * 16 + q * 4 + ss] = acc[ss] + bb;
  __syncthreads();

  for (int k = 0; k < 5; ++k) {
    float p = 0.f;
    for (int i = t; i < 1024; i += 256) p += s_flat[i] * Wl[k * 1024 + i];
#pragma unroll
    for (int off = 32; off; off >>= 1) p += __shfl_down(p, off, 64);
    if ((t & 63) == 0) s_red[t >> 6] = p;
    __syncthreads();
    if (t == 0)
      out[b * 5 + k] = s_red[0] + s_red[1] + s_red[2] + s_red[3] + bl[k];
    __syncthreads();
  }
}

extern "C" void kernel_launch(void* const* d_in, const int* in_sizes, int n_in,
                              void* d_out, int out_size, void* d_ws,
                              size_t ws_size, hipStream_t stream) {
  const float* Fp = (const float*)d_in[0];
  // d_in[1] = W1, d_in[2] = b1  -> dead code in reference, unused.
  const float* W2 = (const float*)d_in[3];
  const float* b2 = (const float*)d_in[4];
  const float* Wl = (const float*)d_in[5];
  const float* bl = (const float*)d_in[6];
  float* out = (float*)d_out;

  float* stat2 = (float*)d_ws; // 1024*192 floats = 768 KB scratch

  stat_kernel<<<3072, 256, 0, stream>>>(Fp, stat2);
  fuse_kernel<<<64, 256, 0, stream>>>(stat2, W2, b2, Wl, bl, out);
}

// Round 2
// 467.385 us; speedup vs baseline: 1.0596x; 1.0596x over previous
//
#include <hip/hip_runtime.h>
#include <hip/hip_bf16.h>

// Problem constants
// B=64, C=16, F=2048, J=25 ; EMBED=64, CLASSES=5, NJ=12
// stats: s2=max, s3=q25(pos 511.75), s4=xs[1023], s5=q75(pos 1535.25),
//        s6=mean, s7=std(ddof=1), s8=max-min, s9=kurtosis
// stat1/W1/b1 path is dead code in the reference. features[...,24] unused.

#define F_LEN 2048
#define JTOT 25
#define STATS_PER_BC 192 // 16 s * 12 j

// ---------------------------------------------------------------------------
// Kernel A: one wave per (bc, j) array. 1024 bc * 24 j = 24576 waves
// = 6144 blocks of 256 threads. In-register wave bitonic sort:
// 64 lanes x 32 regs, blocked layout (lane l holds ranks [32l,32l+32)).
// Sign-flip trick: stages 5..10 have lane-dependent merge direction; we XOR
// the sign bit on descending-block lanes so every comparator is uniform
// min/max (2 VALU instead of 4). Stage 11 is all-ascending by construction.
// ---------------------------------------------------------------------------
__global__ __launch_bounds__(256) void stat_kernel(
    const float* __restrict__ Fp, float* __restrict__ stat2) {
  const int g = blockIdx.x;   // 0..6143
  const int xcd = g & 7;
  const int mm = g >> 3;      // 0..767
  const int bc = xcd * 128 + mm / 6;
  const int grp = mm % 6;     // 0..5
  const int w = threadIdx.x >> 6;
  const int lane = threadIdx.x & 63;
  const int j = grp * 4 + w;  // 0..23

  const float* base =
      Fp + ((size_t)bc * F_LEN + (size_t)lane * 32) * JTOT + j;

  float x[32];
#pragma unroll
  for (int e = 0; e < 32; ++e) x[e] = base[e * JTOT];

  // ---- moments (two-pass central) ----
  float sum = 0.f;
#pragma unroll
  for (int e = 0; e < 32; ++e) sum += x[e];
#pragma unroll
  for (int off = 32; off; off >>= 1) sum += __shfl_xor(sum, off, 64);
  const float m = sum * (1.0f / 2048.0f);

  float c2 = 0.f, c4 = 0.f;
#pragma unroll
  for (int e = 0; e < 32; ++e) {
    float d = x[e] - m;
    float dd = d * d;
    c2 += dd;
    c4 += dd * dd;
  }
#pragma unroll
  for (int off = 32; off; off >>= 1) {
    c2 += __shfl_xor(c2, off, 64);
    c4 += __shfl_xor(c4, off, 64);
  }
  const float var = c2 * (1.0f / 2047.0f);  // ddof=1
  const float sd = sqrtf(var);
  const float kurt = (c4 * (1.0f / 2048.0f)) / (var * var) - 3.0f;

  // ---- bitonic sort ----
  // Stages 1..4: direction depends only on e (compile-time), strides < 32.
#pragma unroll
  for (int kp = 1; kp <= 4; ++kp) {
    const int k = 1 << kp;
#pragma unroll
    for (int jp = kp - 1; jp >= 0; --jp) {
      const int st = 1 << jp;
#pragma unroll
      for (int e = 0; e < 32; ++e) {
        if ((e & st) == 0) {
          const bool up = ((e & k) == 0);
          float a = x[e], b = x[e + st];
          float lo = fminf(a, b), hi = fmaxf(a, b);
          x[e] = up ? lo : hi;
          x[e + st] = up ? hi : lo;
        }
      }
    }
  }

  // Stages 5..10: direction = bit (kp-5) of lane. Sign-flip descending lanes.
  unsigned curflip = 0u;
#pragma unroll
  for (int kp = 5; kp <= 10; ++kp) {
    const unsigned want = ((lane >> (kp - 5)) & 1) ? 0x80000000u : 0u;
    const unsigned fl = want ^ curflip;
    curflip = want;
#pragma unroll
    for (int e = 0; e < 32; ++e)
      x[e] = __uint_as_float(__float_as_uint(x[e]) ^ fl);
#pragma unroll
    for (int jp = kp - 1; jp >= 0; --jp) {
      const int st = 1 << jp;
      if (st >= 32) {
        const int mask = st >> 5;
        const bool keepmin = ((lane & mask) == 0);
#pragma unroll
        for (int e = 0; e < 32; ++e) {
          float o = __shfl_xor(x[e], mask, 64);
          x[e] = keepmin ? fminf(x[e], o) : fmaxf(x[e], o);
        }
      } else {
#pragma unroll
        for (int e = 0; e < 32; ++e) {
          if ((e & st) == 0) {
            float a = x[e], b = x[e + st];
            x[e] = fminf(a, b);
            x[e + st] = fmaxf(a, b);
          }
        }
      }
    }
  }
  // Unflip before the final (all-ascending) stage.
#pragma unroll
  for (int e = 0; e < 32; ++e)
    x[e] = __uint_as_float(__float_as_uint(x[e]) ^ curflip);

  // Stage 11: k=2048, every index has bit 11 == 0 -> uniform ascending.
#pragma unroll
  for (int jp = 10; jp >= 0; --jp) {
    const int st = 1 << jp;
    if (st >= 32) {
      const int mask = st >> 5;
      const bool keepmin = ((lane & mask) == 0);
#pragma unroll
      for (int e = 0; e < 32; ++e) {
        float o = __shfl_xor(x[e], mask, 64);
        x[e] = keepmin ? fminf(x[e], o) : fmaxf(x[e], o);
      }
    } else {
#pragma unroll
      for (int e = 0; e < 32; ++e) {
        if ((e & st) == 0) {
          float a = x[e], b = x[e + st];
          x[e] = fminf(a, b);
          x[e + st] = fmaxf(a, b);
        }
      }
    }
  }

  // ---- extract order statistics (rank r -> lane r>>5, reg r&31) ----
  const float mn    = __shfl(x[0], 0, 64);
  const float a511  = __shfl(x[31], 15, 64);
  const float a512  = __shfl(x[0], 16, 64);
  const float amed  = __shfl(x[31], 31, 64);
  const float a1535 = __shfl(x[31], 47, 64);
  const float a1536 = __shfl(x[0], 48, 64);
  const float mx    = __shfl(x[31], 63, 64);

  if (lane == 0) {
    const float q25 = 0.25f * a511 + 0.75f * a512;    // pos = 511.75
    const float q75 = 0.75f * a1535 + 0.25f * a1536;  // pos = 1535.25
    const int jj = (j < 12) ? j : j - 12;
    const int sb = (j < 12) ? 0 : 8;
    float st[8] = {mx, q25, amed, q75, m, sd, mx - mn, kurt};
    float* o = stat2 + (bc * 16 + sb) * 12 + jj;
#pragma unroll
    for (int s = 0; s < 8; ++s) o[s * 12] = st[s];
  }
}

// ---------------------------------------------------------------------------
// Kernel B: fuse (einsum over c,j with W2 + b2) then logits (@ Wl.T + bl).
// One block per batch element b.
// ---------------------------------------------------------------------------
__global__ __launch_bounds__(256) void fuse_kernel(
    const float* __restrict__ stat2, const float* __restrict__ W2,
    const float* __restrict__ b2, const float* __restrict__ Wl,
    const float* __restrict__ bl, float* __restrict__ out) {
  __shared__ float s_stat[16 * STATS_PER_BC]; // 3072 floats: [c][s][j]
  __shared__ float s_flat[1024];
  __shared__ float s_red[4];

  const int b = blockIdx.x;
  const int t = threadIdx.x;

  for (int idx = t; idx < 16 * STATS_PER_BC; idx += 256)
    s_stat[idx] = stat2[b * (16 * STATS_PER_BC) + idx];
  __syncthreads();

  const int e = t & 63;
  const int q = t >> 6; // s-quarter: s in {4q..4q+3}
  float acc[4] = {0.f, 0.f, 0.f, 0.f};
  for (int c = 0; c < 16; ++c) {
    const float* wrow = W2 + (e * 16 + c) * 12;
    const float* srow = s_stat + c * STATS_PER_BC;
#pragma unroll
    for (int jj = 0; jj < 12; ++jj) {
      const float wv = wrow[jj];
#pragma unroll
      for (int ss = 0; ss < 4; ++ss)
        acc[ss] += srow[(q * 4 + ss) * 12 + jj] * wv;
    }
  }
  const float bb = b2[e];
#pragma unroll
  for (int ss = 0; ss < 4; ++ss)
    s_flat[e * 16 + q * 4 + ss] = acc[ss] + bb;
  __syncthreads();

  for (int k = 0; k < 5; ++k) {
    float p = 0.f;
    for (int i = t; i < 1024; i += 256) p += s_flat[i] * Wl[k * 1024 + i];
#pragma unroll
    for (int off = 32; off; off >>= 1) p += __shfl_down(p, off, 64);
    if ((t & 63) == 0) s_red[t >> 6] = p;
    __syncthreads();
    if (t == 0)
      out[b * 5 + k] = s_red[0] + s_red[1] + s_red[2] + s_red[3] + bl[k];
    __syncthreads();
  }
}

extern "C" void kernel_launch(void* const* d_in, const int* in_sizes, int n_in,
                              void* d_out, int out_size, void* d_ws,
                              size_t ws_size, hipStream_t stream) {
  const float* Fp = (const float*)d_in[0];
  // d_in[1] = W1, d_in[2] = b1  -> dead code in reference, unused.
  const float* W2 = (const float*)d_in[3];
  const float* b2 = (const float*)d_in[4];
  const float* Wl = (const float*)d_in[5];
  const float* bl = (const float*)d_in[6];
  float* out = (float*)d_out;

  float* stat2 = (float*)d_ws; // 1024*192 floats = 768 KB scratch

  stat_kernel<<<6144, 256, 0, stream>>>(Fp, stat2);
  fuse_kernel<<<64, 256, 0, stream>>>(stat2, W2, b2, Wl, bl, out);
}

// Round 3
// 454.860 us; speedup vs baseline: 1.0888x; 1.0275x over previous
//
#include <hip/hip_runtime.h>
#include <hip/hip_bf16.h>
#include <math.h>

// B=64, C=16, F=2048, J=25 ; EMBED=64, CLASSES=5, NJ=12
// stats: s2=max, s3=q25(pos 511.75), s4=xs[1023], s5=q75(pos 1535.25),
//        s6=mean, s7=std(ddof=1), s8=max-min, s9=kurtosis
// stat1/W1/b1 path is dead code in the reference. features[...,24] unused.
//
// Round-3 structure: bitonic stages 1..10 only (two sorted 1024-halves:
// [0..1023] ascending, [1024..2047] descending), then LDS dump + exact
// merge-path selection for ranks {511,512,1023,1535,1536}. Cross-lane CEs
// use the sign-negation trick: role-bit lanes store negated values so every
// lane executes uniform v_min_f32(x, -recv) (neg modifier is free).

#define F_LEN 2048
#define JTOT 25
#define STATS_PER_BC 192 // 16 s * 12 j

// LDS word swizzle: rotate each 32-word row by 4*(row&7) words so the
// 8 ds_write_b128 per lane spread across all 32 banks.
__device__ __forceinline__ int swz(int i) {
  return (i & ~31) | ((i + ((i >> 5) << 2)) & 31);
}

__global__ __launch_bounds__(256) void stat_kernel(
    const float* __restrict__ Fp, float* __restrict__ stat2) {
  __shared__ float lds[4 * 2048]; // 8 KB per wave, private per wave
  const int g = blockIdx.x;   // 0..6143
  const int xcd = g & 7;
  const int mm = g >> 3;
  const int bc = xcd * 128 + mm / 6;
  const int grp = mm % 6;
  const int w = threadIdx.x >> 6;
  const int lane = threadIdx.x & 63;
  const int j = grp * 4 + w;  // 0..23
  float* wlds = lds + w * 2048;

  const float* base =
      Fp + ((size_t)bc * F_LEN + (size_t)lane * 32) * JTOT + j;

  float x[32];
#pragma unroll
  for (int e = 0; e < 32; ++e) x[e] = base[e * JTOT];

  // ---- moments (two-pass central) ----
  float sum = 0.f;
#pragma unroll
  for (int e = 0; e < 32; ++e) sum += x[e];
#pragma unroll
  for (int off = 32; off; off >>= 1) sum += __shfl_xor(sum, off, 64);
  const float m = sum * (1.0f / 2048.0f);

  float c2 = 0.f, c4 = 0.f;
#pragma unroll
  for (int e = 0; e < 32; ++e) {
    float d = x[e] - m;
    float dd = d * d;
    c2 += dd;
    c4 += dd * dd;
  }
#pragma unroll
  for (int off = 32; off; off >>= 1) {
    c2 += __shfl_xor(c2, off, 64);
    c4 += __shfl_xor(c4, off, 64);
  }
  const float var = c2 * (1.0f / 2047.0f);  // ddof=1
  const float sd = sqrtf(var);
  const float kurt = (c4 * (1.0f / 2048.0f)) / (var * var) - 3.0f;

  // ---- bitonic stages 1..4: in-register, direction by e (compile-time) ----
#pragma unroll
  for (int kp = 1; kp <= 4; ++kp) {
    const int k = 1 << kp;
#pragma unroll
    for (int jp = kp - 1; jp >= 0; --jp) {
      const int st = 1 << jp;
#pragma unroll
      for (int e = 0; e < 32; ++e) {
        if ((e & st) == 0) {
          const bool up = ((e & k) == 0);
          float a = x[e], b = x[e + st];
          float lo2 = fminf(a, b), hi2 = fmaxf(a, b);
          x[e] = up ? lo2 : hi2;
          x[e + st] = up ? hi2 : lo2;
        }
      }
    }
  }

  // ---- stages 5..10: running sign-state Fst = direction ^ role ----
  unsigned Fst = 0u;
#pragma unroll
  for (int kp = 5; kp <= 10; ++kp) {
    const unsigned d = ((lane >> (kp - 5)) & 1) ? 0x80000000u : 0u;
    // cross-lane passes (stride >= 32): role-negation trick
#pragma unroll
    for (int jp = kp - 1; jp >= 5; --jp) {
      const int lm = 1 << (jp - 5); // lane xor mask
      const unsigned r = ((lane >> (jp - 5)) & 1) ? 0x80000000u : 0u;
      const unsigned tgt = d ^ r;
      const unsigned fl = tgt ^ Fst;
      Fst = tgt;
#pragma unroll
      for (int e = 0; e < 32; ++e)
        x[e] = __uint_as_float(__float_as_uint(x[e]) ^ fl);
#pragma unroll
      for (int e = 0; e < 32; ++e) {
        float o = __shfl_xor(x[e], lm, 64);
        x[e] = fminf(x[e], -o); // uniform: keeps min (role-0) / -max (role-1)
      }
    }
    // restore to direction-only sign, then in-register passes
    {
      const unsigned fl = d ^ Fst;
      Fst = d;
#pragma unroll
      for (int e = 0; e < 32; ++e)
        x[e] = __uint_as_float(__float_as_uint(x[e]) ^ fl);
    }
#pragma unroll
    for (int jp = (kp - 1 < 4 ? kp - 1 : 4); jp >= 0; --jp) {
      const int st = 1 << jp;
#pragma unroll
      for (int e = 0; e < 32; ++e) {
        if ((e & st) == 0) {
          float a = x[e], b = x[e + st];
          x[e] = fminf(a, b);
          x[e + st] = fmaxf(a, b);
        }
      }
    }
  }
  // unflip direction (Fst == d10)
#pragma unroll
  for (int e = 0; e < 32; ++e)
    x[e] = __uint_as_float(__float_as_uint(x[e]) ^ Fst);

  // ---- dump to LDS: [0..1023] asc, [1024..2047] desc, bank-swizzled ----
  {
    float4* dst4 = (float4*)wlds;
#pragma unroll
    for (int q = 0; q < 8; ++q) {
      int wq = 8 * lane + ((q + lane) & 7); // float4-unit swizzled index
      dst4[wq] = make_float4(x[4 * q], x[4 * q + 1], x[4 * q + 2], x[4 * q + 3]);
    }
  }
  // (same-wave LDS RAW: compiler inserts lgkmcnt wait; region is wave-private)

  // ---- merge-path selection: lane i in 0..4 finds rank k_i ----
  // A[t] = wlds[t] (asc, 1024); B_asc[t] = wlds[2047 - t] (B stored desc).
  const int kk = (lane == 0) ? 511
               : (lane == 1) ? 512
               : (lane == 2) ? 1023
               : (lane == 3) ? 1535 : 1536;
  const int mtot = kk + 1; // take mtot smallest; s = count from A
  int lo = mtot - 1024; if (lo < 0) lo = 0;
  int hi = (mtot < 1024) ? mtot : 1024;
  for (int it = 0; it < 11; ++it) {
    const bool act = lo < hi;
    const int s = (lo + hi) >> 1;
    const int sa = (s < 1023) ? s : 1023;
    float Av = wlds[swz(sa)];
    Av = (s < 1024) ? Av : INFINITY;
    int bidx = mtot - s - 1;
    bidx = bidx < 0 ? 0 : (bidx > 1023 ? 1023 : bidx);
    const float Bv = wlds[swz(2047 - bidx)];
    const bool gg = act && (Bv > Av);
    if (gg) lo = s + 1;
    else if (act) hi = s;
  }
  float val;
  {
    const int s = lo;
    const int ia = (s - 1 < 0) ? 0 : s - 1;
    const float fa = wlds[swz(ia)];
    const float fromA = (s > 0) ? fa : -INFINITY;
    const int bi = mtot - s - 1;
    const int ib = (bi < 0) ? 0 : bi;
    const float fb = wlds[swz(2047 - ib)];
    const float fromB = (bi >= 0) ? fb : -INFINITY;
    val = fmaxf(fromA, fromB);
  }

  const float a511  = __shfl(val, 0, 64);
  const float a512  = __shfl(val, 1, 64);
  const float amed  = __shfl(val, 2, 64);
  const float a1535 = __shfl(val, 3, 64);
  const float a1536 = __shfl(val, 4, 64);

  if (lane == 0) {
    const float mn = fminf(wlds[swz(0)], wlds[swz(2047)]);
    const float mx = fmaxf(wlds[swz(1023)], wlds[swz(1024)]);
    const float q25 = 0.25f * a511 + 0.75f * a512;    // pos = 511.75
    const float q75 = 0.75f * a1535 + 0.25f * a1536;  // pos = 1535.25
    const int jj = (j < 12) ? j : j - 12;
    const int sb = (j < 12) ? 0 : 8;
    float st8[8] = {mx, q25, amed, q75, m, sd, mx - mn, kurt};
    float* o = stat2 + (bc * 16 + sb) * 12 + jj;
#pragma unroll
    for (int s2 = 0; s2 < 8; ++s2) o[s2 * 12] = st8[s2];
  }
}

// ---------------------------------------------------------------------------
// Kernel B: fuse (einsum over c,j with W2 + b2) then logits (@ Wl.T + bl).
// ---------------------------------------------------------------------------
__global__ __launch_bounds__(256) void fuse_kernel(
    const float* __restrict__ stat2, const float* __restrict__ W2,
    const float* __restrict__ b2, const float* __restrict__ Wl,
    const float* __restrict__ bl, float* __restrict__ out) {
  __shared__ float s_stat[16 * STATS_PER_BC]; // 3072 floats: [c][s][j]
  __shared__ float s_flat[1024];
  __shared__ float s_red[4];

  const int b = blockIdx.x;
  const int t = threadIdx.x;

  for (int idx = t; idx < 16 * STATS_PER_BC; idx += 256)
    s_stat[idx] = stat2[b * (16 * STATS_PER_BC) + idx];
  __syncthreads();

  const int e = t & 63;
  const int q = t >> 6;
  float acc[4] = {0.f, 0.f, 0.f, 0.f};
  for (int c = 0; c < 16; ++c) {
    const float* wrow = W2 + (e * 16 + c) * 12;
    const float* srow = s_stat + c * STATS_PER_BC;
#pragma unroll
    for (int jj = 0; jj < 12; ++jj) {
      const float wv = wrow[jj];
#pragma unroll
      for (int ss = 0; ss < 4; ++ss)
        acc[ss] += srow[(q * 4 + ss) * 12 + jj] * wv;
    }
  }
  const float bb = b2[e];
#pragma unroll
  for (int ss = 0; ss < 4; ++ss)
    s_flat[e * 16 + q * 4 + ss] = acc[ss] + bb;
  __syncthreads();

  for (int k = 0; k < 5; ++k) {
    float p = 0.f;
    for (int i = t; i < 1024; i += 256) p += s_flat[i] * Wl[k * 1024 + i];
#pragma unroll
    for (int off = 32; off; off >>= 1) p += __shfl_down(p, off, 64);
    if ((t & 63) == 0) s_red[t >> 6] = p;
    __syncthreads();
    if (t == 0)
      out[b * 5 + k] = s_red[0] + s_red[1] + s_red[2] + s_red[3] + bl[k];
    __syncthreads();
  }
}

extern "C" void kernel_launch(void* const* d_in, const int* in_sizes, int n_in,
                              void* d_out, int out_size, void* d_ws,
                              size_t ws_size, hipStream_t stream) {
  const float* Fp = (const float*)d_in[0];
  // d_in[1] = W1, d_in[2] = b1 -> dead code in reference, unused.
  const float* W2 = (const float*)d_in[3];
  const float* b2 = (const float*)d_in[4];
  const float* Wl = (const float*)d_in[5];
  const float* bl = (const float*)d_in[6];
  float* out = (float*)d_out;

  float* stat2 = (float*)d_ws; // 1024*192 floats = 768 KB scratch

  stat_kernel<<<6144, 256, 0, stream>>>(Fp, stat2);
  fuse_kernel<<<64, 256, 0, stream>>>(stat2, W2, b2, Wl, bl, out);
}

// Round 5
// 449.273 us; speedup vs baseline: 1.1023x; 1.0124x over previous
//
#include <hip/hip_runtime.h>
#include <hip/hip_bf16.h>
#include <math.h>

// B=64, C=16, F=2048, J=25 ; EMBED=64, CLASSES=5, NJ=12
// stats: s2=max, s3=q25(pos 511.75), s4=xs[1023], s5=q75(pos 1535.25),
//        s6=mean, s7=std(ddof=1), s8=max-min, s9=kurtosis
// stat1/W1/b1 path is dead code in the reference. features[...,24] unused.
//
// Round-5: round-4 structure with the staging swizzle FIXED (wrapped
// rotation via swz(), matching the verified merge-dump pattern; round 4's
// unwrapped "+offset" collided rows r%8==7 with r+1). Cooperative
// semi-coalesced global->LDS staging, skewed LDS, in-register bitonic
// stages 1..10, LDS dump, exact merge-path selection.

#define F_LEN 2048
#define JTOT 25
#define STATS_PER_BC 192 // 16 s * 12 j
#define LP 2056          // LDS words per j-region (2048 + 8 so stride%32==8)

// Word swizzle: rotate each 32-word row by 4*(row&7) words, WRAPPED in-row.
__device__ __forceinline__ int swz(int i) {
  return (i & ~31) | ((i + ((i >> 5) << 2)) & 31);
}

__global__ __launch_bounds__(256) void stat_kernel(
    const float* __restrict__ Fp, float* __restrict__ stat2) {
  __shared__ float lds[4 * LP]; // 32,896 B
  const int g = blockIdx.x;     // 0..6143
  const int xcd = g & 7;
  const int mm = g >> 3;
  const int bc = xcd * 128 + mm / 6;
  const int grp = mm % 6;
  const int t = threadIdx.x;
  const int w = t >> 6;
  const int lane = t & 63;
  const int j0 = grp * 4;       // block stages j0..j0+3; wave w sorts j0+w
  float* wlds = lds + w * LP;

  // ---- phase 1: cooperative staging, [f][jj] -> LDS swizzled ----
  {
    const float* bbase = Fp + (size_t)bc * F_LEN * JTOT + j0;
    const int f0 = t >> 2, jj = t & 3;
    float* ldst = lds + jj * LP;
#pragma unroll
    for (int it = 0; it < 32; ++it) {
      const int f = it * 64 + f0;
      ldst[swz(f)] = bbase[(size_t)f * JTOT + jj];
    }
  }
  __syncthreads();

  // ---- phase 2: wave w reads its array as 8 conflict-free float4s ----
  float x[32];
  {
    const float4* src4 = (const float4*)wlds;
#pragma unroll
    for (int q = 0; q < 8; ++q) {
      float4 v = src4[lane * 8 + ((lane + q) & 7)];
      x[4 * q] = v.x; x[4 * q + 1] = v.y;
      x[4 * q + 2] = v.z; x[4 * q + 3] = v.w;
    }
  }

  // ---- moments (two-pass central) ----
  float sum = 0.f;
#pragma unroll
  for (int e = 0; e < 32; ++e) sum += x[e];
#pragma unroll
  for (int off = 32; off; off >>= 1) sum += __shfl_xor(sum, off, 64);
  const float m = sum * (1.0f / 2048.0f);

  float c2 = 0.f, c4 = 0.f;
#pragma unroll
  for (int e = 0; e < 32; ++e) {
    float d = x[e] - m;
    float dd = d * d;
    c2 += dd;
    c4 += dd * dd;
  }
#pragma unroll
  for (int off = 32; off; off >>= 1) {
    c2 += __shfl_xor(c2, off, 64);
    c4 += __shfl_xor(c4, off, 64);
  }
  const float var = c2 * (1.0f / 2047.0f);  // ddof=1
  const float sd = sqrtf(var);
  const float kurt = (c4 * (1.0f / 2048.0f)) / (var * var) - 3.0f;

  // ---- bitonic stages 1..4: in-register, direction by e (compile-time) ----
#pragma unroll
  for (int kp = 1; kp <= 4; ++kp) {
    const int k = 1 << kp;
#pragma unroll
    for (int jp = kp - 1; jp >= 0; --jp) {
      const int st = 1 << jp;
#pragma unroll
      for (int e = 0; e < 32; ++e) {
        if ((e & st) == 0) {
          const bool up = ((e & k) == 0);
          float a = x[e], b = x[e + st];
          float lo2 = fminf(a, b), hi2 = fmaxf(a, b);
          x[e] = up ? lo2 : hi2;
          x[e + st] = up ? hi2 : lo2;
        }
      }
    }
  }

  // ---- stages 5..10: running sign-state Fst = direction ^ role ----
  unsigned Fst = 0u;
#pragma unroll
  for (int kp = 5; kp <= 10; ++kp) {
    const unsigned d = ((lane >> (kp - 5)) & 1) ? 0x80000000u : 0u;
#pragma unroll
    for (int jp = kp - 1; jp >= 5; --jp) {
      const int lm = 1 << (jp - 5);
      const unsigned r = ((lane >> (jp - 5)) & 1) ? 0x80000000u : 0u;
      const unsigned tgt = d ^ r;
      const unsigned fl = tgt ^ Fst;
      Fst = tgt;
#pragma unroll
      for (int e = 0; e < 32; ++e)
        x[e] = __uint_as_float(__float_as_uint(x[e]) ^ fl);
#pragma unroll
      for (int e = 0; e < 32; ++e) {
        float o = __shfl_xor(x[e], lm, 64);
        x[e] = fminf(x[e], -o); // uniform: keeps min (role-0) / -max (role-1)
      }
    }
    {
      const unsigned fl = d ^ Fst;
      Fst = d;
#pragma unroll
      for (int e = 0; e < 32; ++e)
        x[e] = __uint_as_float(__float_as_uint(x[e]) ^ fl);
    }
#pragma unroll
    for (int jp = (kp - 1 < 4 ? kp - 1 : 4); jp >= 0; --jp) {
      const int st = 1 << jp;
#pragma unroll
      for (int e = 0; e < 32; ++e) {
        if ((e & st) == 0) {
          float a = x[e], b = x[e + st];
          x[e] = fminf(a, b);
          x[e + st] = fmaxf(a, b);
        }
      }
    }
  }
#pragma unroll
  for (int e = 0; e < 32; ++e)
    x[e] = __uint_as_float(__float_as_uint(x[e]) ^ Fst);

  // ---- dump to LDS (region w now wave-private): [0..1023] asc,
  //      [1024..2047] desc, same wrapped swizzle ----
  {
    float4* dst4 = (float4*)wlds;
#pragma unroll
    for (int q = 0; q < 8; ++q) {
      int wq = 8 * lane + ((q + lane) & 7);
      dst4[wq] = make_float4(x[4 * q], x[4 * q + 1], x[4 * q + 2], x[4 * q + 3]);
    }
  }

  // ---- merge-path selection: lane i in 0..4 finds rank k_i ----
  const int kk = (lane == 0) ? 511
               : (lane == 1) ? 512
               : (lane == 2) ? 1023
               : (lane == 3) ? 1535 : 1536;
  const int mtot = kk + 1;
  int lo = mtot - 1024; if (lo < 0) lo = 0;
  int hi = (mtot < 1024) ? mtot : 1024;
  for (int it = 0; it < 11; ++it) {
    const bool act = lo < hi;
    const int s = (lo + hi) >> 1;
    const int sa = (s < 1023) ? s : 1023;
    float Av = wlds[swz(sa)];
    Av = (s < 1024) ? Av : INFINITY;
    int bidx = mtot - s - 1;
    bidx = bidx < 0 ? 0 : (bidx > 1023 ? 1023 : bidx);
    const float Bv = wlds[swz(2047 - bidx)];
    const bool gg = act && (Bv > Av);
    if (gg) lo = s + 1;
    else if (act) hi = s;
  }
  float val;
  {
    const int s = lo;
    const int ia = (s - 1 < 0) ? 0 : s - 1;
    const float fa = wlds[swz(ia)];
    const float fromA = (s > 0) ? fa : -INFINITY;
    const int bi = mtot - s - 1;
    const int ib = (bi < 0) ? 0 : bi;
    const float fb = wlds[swz(2047 - ib)];
    const float fromB = (bi >= 0) ? fb : -INFINITY;
    val = fmaxf(fromA, fromB);
  }

  const float a511  = __shfl(val, 0, 64);
  const float a512  = __shfl(val, 1, 64);
  const float amed  = __shfl(val, 2, 64);
  const float a1535 = __shfl(val, 3, 64);
  const float a1536 = __shfl(val, 4, 64);

  if (lane == 0) {
    const float mn = fminf(wlds[swz(0)], wlds[swz(2047)]);
    const float mx = fmaxf(wlds[swz(1023)], wlds[swz(1024)]);
    const float q25 = 0.25f * a511 + 0.75f * a512;    // pos = 511.75
    const float q75 = 0.75f * a1535 + 0.25f * a1536;  // pos = 1535.25
    const int j = j0 + w;
    const int jj = (j < 12) ? j : j - 12;
    const int sb = (j < 12) ? 0 : 8;
    float st8[8] = {mx, q25, amed, q75, m, sd, mx - mn, kurt};
    float* o = stat2 + (bc * 16 + sb) * 12 + jj;
#pragma unroll
    for (int s2 = 0; s2 < 8; ++s2) o[s2 * 12] = st8[s2];
  }
}

// ---------------------------------------------------------------------------
// Kernel B: fuse (einsum over c,j with W2 + b2) then logits (@ Wl.T + bl).
// ---------------------------------------------------------------------------
__global__ __launch_bounds__(256) void fuse_kernel(
    const float* __restrict__ stat2, const float* __restrict__ W2,
    const float* __restrict__ b2, const float* __restrict__ Wl,
    const float* __restrict__ bl, float* __restrict__ out) {
  __shared__ float s_stat[16 * STATS_PER_BC];
  __shared__ float s_flat[1024];
  __shared__ float s_red[4];

  const int b = blockIdx.x;
  const int t = threadIdx.x;

  for (int idx = t; idx < 16 * STATS_PER_BC; idx += 256)
    s_stat[idx] = stat2[b * (16 * STATS_PER_BC) + idx];
  __syncthreads();

  const int e = t & 63;
  const int q = t >> 6;
  float acc[4] = {0.f, 0.f, 0.f, 0.f};
  for (int c = 0; c < 16; ++c) {
    const float* wrow = W2 + (e * 16 + c) * 12;
    const float* srow = s_stat + c * STATS_PER_BC;
#pragma unroll
    for (int jj = 0; jj < 12; ++jj) {
      const float wv = wrow[jj];
#pragma unroll
      for (int ss = 0; ss < 4; ++ss)
        acc[ss] += srow[(q * 4 + ss) * 12 + jj] * wv;
    }
  }
  const float bb = b2[e];
#pragma unroll
  for (int ss = 0; ss < 4; ++ss)
    s_flat[e * 16 + q * 4 + ss] = acc[ss] + bb;
  __syncthreads();

  for (int k = 0; k < 5; ++k) {
    float p = 0.f;
    for (int i = t; i < 1024; i += 256) p += s_flat[i] * Wl[k * 1024 + i];
#pragma unroll
    for (int off = 32; off; off >>= 1) p += __shfl_down(p, off, 64);
    if ((t & 63) == 0) s_red[t >> 6] = p;
    __syncthreads();
    if (t == 0)
      out[b * 5 + k] = s_red[0] + s_red[1] + s_red[2] + s_red[3] + bl[k];
    __syncthreads();
  }
}

extern "C" void kernel_launch(void* const* d_in, const int* in_sizes, int n_in,
                              void* d_out, int out_size, void* d_ws,
                              size_t ws_size, hipStream_t stream) {
  const float* Fp = (const float*)d_in[0];
  // d_in[1] = W1, d_in[2] = b1 -> dead code in reference, unused.
  const float* W2 = (const float*)d_in[3];
  const float* b2 = (const float*)d_in[4];
  const float* Wl = (const float*)d_in[5];
  const float* bl = (const float*)d_in[6];
  float* out = (float*)d_out;

  float* stat2 = (float*)d_ws; // 1024*192 floats = 768 KB scratch

  stat_kernel<<<6144, 256, 0, stream>>>(Fp, stat2);
  fuse_kernel<<<64, 256, 0, stream>>>(stat2, W2, b2, Wl, bl, out);
}

// Round 6
// 442.878 us; speedup vs baseline: 1.1183x; 1.0144x over previous
//
#include <hip/hip_runtime.h>
#include <hip/hip_bf16.h>
#include <math.h>

// B=64, C=16, F=2048, J=25 ; EMBED=64, CLASSES=5, NJ=12
// stats: s2=max, s3=q25(pos 511.75), s4=xs[1023], s5=q75(pos 1535.25),
//        s6=mean, s7=std(ddof=1), s8=max-min, s9=kurtosis
// stat1/W1/b1 path is dead code in the reference. features[...,24] unused.
//
// Round-6: identical structure to round-5 (staged loads, bitonic stages
// 1..10, merge-path selection) but ALL cross-lane moves now use
// ds_swizzle_b32 with immediate XOR patterns (mask<=16 never crosses the
// 32-lane half) instead of __shfl_xor, whose ROCm lowering costs ~4-6 VALU
// (mbcnt lane-id + xor + clamp + shl) per call. Off=32 reduction steps use
// ds_bpermute with a once-computed byte address.

#define F_LEN 2048
#define JTOT 25
#define STATS_PER_BC 192 // 16 s * 12 j
#define LP 2056          // LDS words per j-region (2048 + 8 so stride%32==8)

// Word swizzle: rotate each 32-word row by 4*(row&7) words, WRAPPED in-row.
__device__ __forceinline__ int swz(int i) {
  return (i & ~31) | ((i + ((i >> 5) << 2)) & 31);
}

// ds_swizzle with immediate xor pattern (BitMode: offset=(xor<<10)|0x1F).
template <int PAT>
__device__ __forceinline__ float ds_swz(float v) {
  return __int_as_float(
      __builtin_amdgcn_ds_swizzle(__float_as_int(v), PAT));
}
// xor-partner for lane-mask lm in {1,2,4,8,16}; folds under full unroll.
__device__ __forceinline__ float swzxor(float v, const int lm) {
  switch (lm) {
    case 1:  return ds_swz<0x041F>(v);
    case 2:  return ds_swz<0x081F>(v);
    case 4:  return ds_swz<0x101F>(v);
    case 8:  return ds_swz<0x201F>(v);
    default: return ds_swz<0x401F>(v);
  }
}
// full 64-lane sum: 5 swizzles + 1 bpermute (addr32 = (lane^32)<<2).
__device__ __forceinline__ float wave_sum(float v, int addr32) {
  v += ds_swz<0x041F>(v);
  v += ds_swz<0x081F>(v);
  v += ds_swz<0x101F>(v);
  v += ds_swz<0x201F>(v);
  v += ds_swz<0x401F>(v);
  v += __int_as_float(
      __builtin_amdgcn_ds_bpermute(addr32, __float_as_int(v)));
  return v;
}

__global__ __launch_bounds__(256) void stat_kernel(
    const float* __restrict__ Fp, float* __restrict__ stat2) {
  __shared__ float lds[4 * LP]; // 32,896 B
  const int g = blockIdx.x;     // 0..6143
  const int xcd = g & 7;
  const int mm = g >> 3;
  const int bc = xcd * 128 + mm / 6;
  const int grp = mm % 6;
  const int t = threadIdx.x;
  const int w = t >> 6;
  const int lane = t & 63;
  const int addr32 = ((lane ^ 32) << 2);
  const int j0 = grp * 4;       // block stages j0..j0+3; wave w sorts j0+w
  float* wlds = lds + w * LP;

  // ---- phase 1: cooperative staging, [f][jj] -> LDS swizzled ----
  {
    const float* bbase = Fp + (size_t)bc * F_LEN * JTOT + j0;
    const int f0 = t >> 2, jj = t & 3;
    float* ldst = lds + jj * LP;
#pragma unroll
    for (int it = 0; it < 32; ++it) {
      const int f = it * 64 + f0;
      ldst[swz(f)] = bbase[(size_t)f * JTOT + jj];
    }
  }
  __syncthreads();

  // ---- phase 2: wave w reads its array as 8 conflict-free float4s ----
  float x[32];
  {
    const float4* src4 = (const float4*)wlds;
#pragma unroll
    for (int q = 0; q < 8; ++q) {
      float4 v = src4[lane * 8 + ((lane + q) & 7)];
      x[4 * q] = v.x; x[4 * q + 1] = v.y;
      x[4 * q + 2] = v.z; x[4 * q + 3] = v.w;
    }
  }

  // ---- moments (two-pass central) ----
  float sum = 0.f;
#pragma unroll
  for (int e = 0; e < 32; ++e) sum += x[e];
  sum = wave_sum(sum, addr32);
  const float m = sum * (1.0f / 2048.0f);

  float c2 = 0.f, c4 = 0.f;
#pragma unroll
  for (int e = 0; e < 32; ++e) {
    float d = x[e] - m;
    float dd = d * d;
    c2 += dd;
    c4 += dd * dd;
  }
  c2 = wave_sum(c2, addr32);
  c4 = wave_sum(c4, addr32);
  const float var = c2 * (1.0f / 2047.0f);  // ddof=1
  const float sd = sqrtf(var);
  const float kurt = (c4 * (1.0f / 2048.0f)) / (var * var) - 3.0f;

  // ---- bitonic stages 1..4: in-register, direction by e (compile-time) ----
#pragma unroll
  for (int kp = 1; kp <= 4; ++kp) {
    const int k = 1 << kp;
#pragma unroll
    for (int jp = kp - 1; jp >= 0; --jp) {
      const int st = 1 << jp;
#pragma unroll
      for (int e = 0; e < 32; ++e) {
        if ((e & st) == 0) {
          const bool up = ((e & k) == 0);
          float a = x[e], b = x[e + st];
          float lo2 = fminf(a, b), hi2 = fmaxf(a, b);
          x[e] = up ? lo2 : hi2;
          x[e + st] = up ? hi2 : lo2;
        }
      }
    }
  }

  // ---- stages 5..10: running sign-state Fst = direction ^ role ----
  unsigned Fst = 0u;
#pragma unroll
  for (int kp = 5; kp <= 10; ++kp) {
    const unsigned d = ((lane >> (kp - 5)) & 1) ? 0x80000000u : 0u;
#pragma unroll
    for (int jp = kp - 1; jp >= 5; --jp) {
      const int lm = 1 << (jp - 5);  // 1,2,4,8,16 — never crosses half-wave
      const unsigned r = ((lane >> (jp - 5)) & 1) ? 0x80000000u : 0u;
      const unsigned tgt = d ^ r;
      const unsigned fl = tgt ^ Fst;
      Fst = tgt;
#pragma unroll
      for (int e = 0; e < 32; ++e)
        x[e] = __uint_as_float(__float_as_uint(x[e]) ^ fl);
#pragma unroll
      for (int e = 0; e < 32; ++e) {
        float o = swzxor(x[e], lm);
        x[e] = fminf(x[e], -o); // uniform: keeps min (role-0) / -max (role-1)
      }
    }
    {
      const unsigned fl = d ^ Fst;
      Fst = d;
#pragma unroll
      for (int e = 0; e < 32; ++e)
        x[e] = __uint_as_float(__float_as_uint(x[e]) ^ fl);
    }
#pragma unroll
    for (int jp = (kp - 1 < 4 ? kp - 1 : 4); jp >= 0; --jp) {
      const int st = 1 << jp;
#pragma unroll
      for (int e = 0; e < 32; ++e) {
        if ((e & st) == 0) {
          float a = x[e], b = x[e + st];
          x[e] = fminf(a, b);
          x[e + st] = fmaxf(a, b);
        }
      }
    }
  }
#pragma unroll
  for (int e = 0; e < 32; ++e)
    x[e] = __uint_as_float(__float_as_uint(x[e]) ^ Fst);

  // ---- dump to LDS (region w now wave-private): [0..1023] asc,
  //      [1024..2047] desc, same wrapped swizzle ----
  {
    float4* dst4 = (float4*)wlds;
#pragma unroll
    for (int q = 0; q < 8; ++q) {
      int wq = 8 * lane + ((q + lane) & 7);
      dst4[wq] = make_float4(x[4 * q], x[4 * q + 1], x[4 * q + 2], x[4 * q + 3]);
    }
  }

  // ---- merge-path selection: lane i in 0..4 finds rank k_i ----
  const int kk = (lane == 0) ? 511
               : (lane == 1) ? 512
               : (lane == 2) ? 1023
               : (lane == 3) ? 1535 : 1536;
  const int mtot = kk + 1;
  int lo = mtot - 1024; if (lo < 0) lo = 0;
  int hi = (mtot < 1024) ? mtot : 1024;
  for (int it = 0; it < 11; ++it) {
    const bool act = lo < hi;
    const int s = (lo + hi) >> 1;
    const int sa = (s < 1023) ? s : 1023;
    float Av = wlds[swz(sa)];
    Av = (s < 1024) ? Av : INFINITY;
    int bidx = mtot - s - 1;
    bidx = bidx < 0 ? 0 : (bidx > 1023 ? 1023 : bidx);
    const float Bv = wlds[swz(2047 - bidx)];
    const bool gg = act && (Bv > Av);
    if (gg) lo = s + 1;
    else if (act) hi = s;
  }
  float val;
  {
    const int s = lo;
    const int ia = (s - 1 < 0) ? 0 : s - 1;
    const float fa = wlds[swz(ia)];
    const float fromA = (s > 0) ? fa : -INFINITY;
    const int bi = mtot - s - 1;
    const int ib = (bi < 0) ? 0 : bi;
    const float fb = wlds[swz(2047 - ib)];
    const float fromB = (bi >= 0) ? fb : -INFINITY;
    val = fmaxf(fromA, fromB);
  }

  const float a511  = __shfl(val, 0, 64);
  const float a512  = __shfl(val, 1, 64);
  const float amed  = __shfl(val, 2, 64);
  const float a1535 = __shfl(val, 3, 64);
  const float a1536 = __shfl(val, 4, 64);

  if (lane == 0) {
    const float mn = fminf(wlds[swz(0)], wlds[swz(2047)]);
    const float mx = fmaxf(wlds[swz(1023)], wlds[swz(1024)]);
    const float q25 = 0.25f * a511 + 0.75f * a512;    // pos = 511.75
    const float q75 = 0.75f * a1535 + 0.25f * a1536;  // pos = 1535.25
    const int j = j0 + w;
    const int jj = (j < 12) ? j : j - 12;
    const int sb = (j < 12) ? 0 : 8;
    float st8[8] = {mx, q25, amed, q75, m, sd, mx - mn, kurt};
    float* o = stat2 + (bc * 16 + sb) * 12 + jj;
#pragma unroll
    for (int s2 = 0; s2 < 8; ++s2) o[s2 * 12] = st8[s2];
  }
}

// ---------------------------------------------------------------------------
// Kernel B: fuse (einsum over c,j with W2 + b2) then logits (@ Wl.T + bl).
// ---------------------------------------------------------------------------
__global__ __launch_bounds__(256) void fuse_kernel(
    const float* __restrict__ stat2, const float* __restrict__ W2,
    const float* __restrict__ b2, const float* __restrict__ Wl,
    const float* __restrict__ bl, float* __restrict__ out) {
  __shared__ float s_stat[16 * STATS_PER_BC];
  __shared__ float s_flat[1024];
  __shared__ float s_red[4];

  const int b = blockIdx.x;
  const int t = threadIdx.x;

  for (int idx = t; idx < 16 * STATS_PER_BC; idx += 256)
    s_stat[idx] = stat2[b * (16 * STATS_PER_BC) + idx];
  __syncthreads();

  const int e = t & 63;
  const int q = t >> 6;
  float acc[4] = {0.f, 0.f, 0.f, 0.f};
  for (int c = 0; c < 16; ++c) {
    const float* wrow = W2 + (e * 16 + c) * 12;
    const float* srow = s_stat + c * STATS_PER_BC;
#pragma unroll
    for (int jj = 0; jj < 12; ++jj) {
      const float wv = wrow[jj];
#pragma unroll
      for (int ss = 0; ss < 4; ++ss)
        acc[ss] += srow[(q * 4 + ss) * 12 + jj] * wv;
    }
  }
  const float bb = b2[e];
#pragma unroll
  for (int ss = 0; ss < 4; ++ss)
    s_flat[e * 16 + q * 4 + ss] = acc[ss] + bb;
  __syncthreads();

  for (int k = 0; k < 5; ++k) {
    float p = 0.f;
    for (int i = t; i < 1024; i += 256) p += s_flat[i] * Wl[k * 1024 + i];
#pragma unroll
    for (int off = 32; off; off >>= 1) p += __shfl_down(p, off, 64);
    if ((t & 63) == 0) s_red[t >> 6] = p;
    __syncthreads();
    if (t == 0)
      out[b * 5 + k] = s_red[0] + s_red[1] + s_red[2] + s_red[3] + bl[k];
    __syncthreads();
  }
}

extern "C" void kernel_launch(void* const* d_in, const int* in_sizes, int n_in,
                              void* d_out, int out_size, void* d_ws,
                              size_t ws_size, hipStream_t stream) {
  const float* Fp = (const float*)d_in[0];
  // d_in[1] = W1, d_in[2] = b1 -> dead code in reference, unused.
  const float* W2 = (const float*)d_in[3];
  const float* b2 = (const float*)d_in[4];
  const float* Wl = (const float*)d_in[5];
  const float* bl = (const float*)d_in[6];
  float* out = (float*)d_out;

  float* stat2 = (float*)d_ws; // 1024*192 floats = 768 KB scratch

  stat_kernel<<<6144, 256, 0, stream>>>(Fp, stat2);
  fuse_kernel<<<64, 256, 0, stream>>>(stat2, W2, b2, Wl, bl, out);
}